// Round 8
// baseline (1076.407 us; speedup 1.0000x reference)
//
#include <hip/hip_runtime.h>
#include <stdint.h>

#define KCODES 8192
#define DIM 256
#define BM 128           // rows per block; 8 waves: 4 row-groups x 2 col-halves
#define BN 128           // codebook cols per kt tile
#define NTHREADS 512
#define NKT (KCODES / BN)   // 64 tiles
#define NQ (NKT * 8)        // 512 chunk-steps

typedef _Float16 h16;
typedef __attribute__((ext_vector_type(8))) _Float16 f16x8;
typedef __attribute__((ext_vector_type(4))) float f32x4;

__device__ __forceinline__ void split8(const float* __restrict__ x, f16x8& h, f16x8& l) {
    #pragma unroll
    for (int i = 0; i < 8; ++i) {
        float v = x[i];
        _Float16 hv = (_Float16)v;          // RNE
        h[i] = hv;
        l[i] = (_Float16)(v - (float)hv);   // exact residual in f32, RNE to f16
    }
}

// ---------------- c2 kernel: c2h[k] = 0.5 * |codebook[k]|^2 ----------------
__global__ __launch_bounds__(256) void c2_kernel(const float* __restrict__ cb,
                                                 float* __restrict__ c2h, int K) {
    int w = (blockIdx.x * blockDim.x + threadIdx.x) >> 6;
    int lane = threadIdx.x & 63;
    if (w >= K) return;
    const float4 v = *(const float4*)(cb + (size_t)w * DIM + lane * 4);
    float s = v.x * v.x + v.y * v.y + v.z * v.z + v.w * v.w;
    #pragma unroll
    for (int off = 32; off > 0; off >>= 1) s += __shfl_down(s, off);
    if (lane == 0) c2h[w] = 0.5f * s;
}

// ---------------- pack kernel: codebook -> pre-split, pre-swizzled image ----
// 512 chunk-blocks of 16 KB; chunk-block (kt*8+chunk) at h16 offset
// col*64 + p*8 holds: s = p ^ (col&7); s<4 -> f16-high of d [chunk*32+s*8..+7]
// of code kt*128+col; s>=4 -> f16-low residual. (Unchanged since R5.)
__global__ __launch_bounds__(256) void pack_kernel(const float* __restrict__ cb,
                                                   h16* __restrict__ Bp) {
    const int tid = blockIdx.x * 256 + threadIdx.x;
    const int code = tid >> 5;
    const int grp = tid & 31;
    float x[8];
    *(float4*)&x[0] = *(const float4*)(cb + (size_t)code * DIM + grp * 8);
    *(float4*)&x[4] = *(const float4*)(cb + (size_t)code * DIM + grp * 8 + 4);
    f16x8 hh, ll;
    split8(x, hh, ll);
    const int kt = code >> 7, col = code & 127;
    const int chunk = grp >> 2, s = grp & 3;
    const int ph = s ^ (col & 7), pl = (s + 4) ^ (col & 7);
    h16* base = Bp + ((size_t)(kt * 8 + chunk) * 8192) + col * 64;
    *(f16x8*)(base + ph * 8) = hh;
    *(f16x8*)(base + pl * 8) = ll;
}

// ---------------- main MFMA kernel ----------------
// R6 structure at 512 threads: wave tile 32x64 (2m x 4n of 16x16x32),
// A pre-split in regs, B streams via global_load_lds into ring-3 x 16 KB,
// counted vmcnt(2) keeps prefetch in flight across barriers.
// 3-pass split product (hh + hl + lh; ll term ~1e-6 << top-2 gaps ~1e-2).
__global__ __launch_bounds__(NTHREADS, 4) void vq_mfma_pk(
    const float* __restrict__ rep, const h16* __restrict__ Bp,
    const float* __restrict__ c2h, int* __restrict__ out) {

    __shared__ __align__(16) h16 ring[3][8192];   // 48 KB

    const int t = threadIdx.x;
    const int lane = t & 63;
    const int c15 = lane & 15;
    const int g = lane >> 4;              // k-group 0..3
    const int w = t >> 6;                 // wave 0..7
    const int wrow = (w >> 1) * 32;       // row group 0,32,64,96
    const int wcol = (w & 1) * 64;        // col half 0/64
    const int row0 = blockIdx.x * BM;

    // ---- A fragments: 2 row-subtiles x 8 chunks, load + split once ----
    f16x8 ah[2][8], al[2][8];
    #pragma unroll
    for (int m = 0; m < 2; ++m) {
        const float* ar = rep + (size_t)(row0 + wrow + m * 16 + c15) * DIM + g * 8;
        #pragma unroll
        for (int ch = 0; ch < 8; ++ch) {
            float x[8];
            *(float4*)&x[0] = *(const float4*)(ar + ch * 32);
            *(float4*)&x[4] = *(const float4*)(ar + ch * 32 + 4);
            split8(x, ah[m][ch], al[m][ch]);
        }
    }

    f32x4 acc[2][4];
    float best[2][4], cc[4];
    int bidx[2][4];
    #pragma unroll
    for (int m = 0; m < 2; ++m)
        #pragma unroll
        for (int n = 0; n < 4; ++n)
            #pragma unroll
            for (int r = 0; r < 4; ++r) acc[m][n][r] = 0.f;
    #pragma unroll
    for (int m = 0; m < 2; ++m)
        #pragma unroll
        for (int r = 0; r < 4; ++r) { best[m][r] = -3.4e38f; bidx[m][r] = 0; }

    // 512 threads cover a 16 KB chunk with 2 x 16B each
    auto issueB = [&](int q2, int slot) {
        const h16* src = Bp + (size_t)q2 * 8192 + t * 8;
        h16* dst = &ring[slot][t * 8];
        #pragma unroll
        for (int i = 0; i < 2; ++i)
            __builtin_amdgcn_global_load_lds(
                (const __attribute__((address_space(1))) uint32_t*)(src + i * 4096),
                (__attribute__((address_space(3))) uint32_t*)(dst + i * 4096),
                16, 0, 0);
    };

    // drain prologue A-loads so vmcnt counting below is exact
    asm volatile("s_waitcnt vmcnt(0)" ::: "memory");
    issueB(0, 0);
    issueB(1, 1);

    int bufq = 0;
    #pragma unroll 1
    for (int kt = 0; kt < NKT; ++kt) {
        const int ktbase = kt * BN;
        #pragma unroll
        for (int chunk = 0; chunk < 8; ++chunk) {
            const int q = kt * 8 + chunk;
            // q's 2 loads issued 2 steps ago; newest 2 outstanding are q+1's
            // prefetch -> vmcnt(2) proves q landed (cc loads are older and
            // get drained by the same wait). lgkmcnt(0) drains my ds_reads
            // before the rendezvous (ring-slot overwrite hazard).
            if (q == NQ - 1) asm volatile("s_waitcnt vmcnt(0) lgkmcnt(0)" ::: "memory");
            else             asm volatile("s_waitcnt vmcnt(2) lgkmcnt(0)" ::: "memory");
            __builtin_amdgcn_s_barrier();
            __builtin_amdgcn_sched_barrier(0);   // rule 18: nothing crosses

            // cc BEFORE issueB so the newest 2 vmcnt entries stay the prefetch
            if (chunk == 0) {
                #pragma unroll
                for (int n = 0; n < 4; ++n) cc[n] = c2h[ktbase + wcol + n * 16 + c15];
            }
            if (q + 2 < NQ) {
                int slot = bufq + 2;
                if (slot >= 3) slot -= 3;
                issueB(q + 2, slot);
            }

            const h16* lb = &ring[bufq][0];
            #pragma unroll
            for (int n = 0; n < 4; ++n) {
                const int base = (wcol + n * 16 + c15) * 64;
                f16x8 bh = *(const f16x8*)&lb[base + ((g ^ (lane & 7)) << 3)];
                f16x8 bl = *(const f16x8*)&lb[base + (((4 + g) ^ (lane & 7)) << 3)];
                #pragma unroll
                for (int m = 0; m < 2; ++m) {
                    acc[m][n] = __builtin_amdgcn_mfma_f32_16x16x32_f16(ah[m][chunk], bh, acc[m][n], 0, 0, 0);
                    acc[m][n] = __builtin_amdgcn_mfma_f32_16x16x32_f16(ah[m][chunk], bl, acc[m][n], 0, 0, 0);
                    acc[m][n] = __builtin_amdgcn_mfma_f32_16x16x32_f16(al[m][chunk], bh, acc[m][n], 0, 0, 0);
                }
            }

            if (chunk == 7) {   // per-kt argmin epilogue (strict '>' = np tie rule)
                #pragma unroll
                for (int n = 0; n < 4; ++n) {
                    const int col = ktbase + wcol + n * 16 + c15;
                    #pragma unroll
                    for (int m = 0; m < 2; ++m)
                        #pragma unroll
                        for (int r = 0; r < 4; ++r) {
                            float s2 = acc[m][n][r] - cc[n];
                            if (s2 > best[m][r]) { best[m][r] = s2; bidx[m][r] = col; }
                            acc[m][n][r] = 0.f;
                        }
                }
            }
            bufq = (bufq + 1 == 3) ? 0 : bufq + 1;
        }
    }

    // ---- final reduce ----
    // Step 1: shfl across the 16 col-lanes (tie -> lower idx).
    // Step 2: two col-half waves cover each row -> combine via LDS scratch.
    // ring[0] is safe: after the q=511 barrier every wave reads ring[1] only.
    float* sv = (float*)&ring[0][0];      // [row 0..127][half 0..1]
    int* si = (int*)&ring[0][1024];
    #pragma unroll
    for (int m = 0; m < 2; ++m)
        #pragma unroll
        for (int r = 0; r < 4; ++r) {
            float bv = best[m][r];
            int bi = bidx[m][r];
            #pragma unroll
            for (int mask = 1; mask <= 8; mask <<= 1) {
                float ov = __shfl_xor(bv, mask);
                int oi = __shfl_xor(bi, mask);
                if (ov > bv || (ov == bv && oi < bi)) { bv = ov; bi = oi; }
            }
            if (c15 == 0) {
                const int rl = wrow + m * 16 + g * 4 + r;   // 0..127
                sv[rl * 2 + (w & 1)] = bv;
                si[rl * 2 + (w & 1)] = bi;
            }
        }
    __syncthreads();
    if (t < BM) {
        float va = sv[t * 2 + 0], vb = sv[t * 2 + 1];
        int ia = si[t * 2 + 0], ib = si[t * 2 + 1];
        bool pickb = (vb > va) || (vb == va && ib < ia);
        out[row0 + t] = pickb ? ib : ia;
    }
}

extern "C" void kernel_launch(void* const* d_in, const int* in_sizes, int n_in,
                              void* d_out, int out_size, void* d_ws, size_t ws_size,
                              hipStream_t stream) {
    const float* rep = (const float*)d_in[0];
    const float* cb = (const float*)d_in[1];
    const int N = in_sizes[0] / DIM;   // 65536
    const int K = in_sizes[1] / DIM;   // 8192
    float* c2h = (float*)d_ws;         // 32 KB
    h16* Bp = (h16*)((char*)d_ws + 32768);   // 8 MB (ws >= 8.4 MB, proven R5)
    int* out = (int*)d_out;

    c2_kernel<<<dim3((K * 64 + 255) / 256), dim3(256), 0, stream>>>(cb, c2h, K);
    pack_kernel<<<dim3(KCODES * 32 / 256), dim3(256), 0, stream>>>(cb, Bp);
    vq_mfma_pk<<<dim3(N / BM), dim3(NTHREADS), 0, stream>>>(rep, Bp, c2h, out);
}

// Round 9
// 631.457 us; speedup vs baseline: 1.7046x; 1.7046x over previous
//
#include <hip/hip_runtime.h>
#include <stdint.h>

#define KCODES 8192
#define DIM 256
#define BM 128           // rows per block; 8 waves: 4 row-groups x 2 col-halves
#define BN 128           // codebook cols per kt tile
#define NTHREADS 512
#define NKT (KCODES / BN)   // 64 tiles
#define NQ (NKT * 8)        // 512 chunk-steps

typedef _Float16 h16;
typedef __attribute__((ext_vector_type(8))) _Float16 f16x8;
typedef __attribute__((ext_vector_type(4))) float f32x4;

__device__ __forceinline__ void split8(const float* __restrict__ x, f16x8& h, f16x8& l) {
    #pragma unroll
    for (int i = 0; i < 8; ++i) {
        float v = x[i];
        _Float16 hv = (_Float16)v;          // RNE
        h[i] = hv;
        l[i] = (_Float16)(v - (float)hv);   // exact residual in f32, RNE to f16
    }
}

// ---------------- c2 kernel: c2h[k] = 0.5 * |codebook[k]|^2 ----------------
__global__ __launch_bounds__(256) void c2_kernel(const float* __restrict__ cb,
                                                 float* __restrict__ c2h, int K) {
    int w = (blockIdx.x * blockDim.x + threadIdx.x) >> 6;
    int lane = threadIdx.x & 63;
    if (w >= K) return;
    const float4 v = *(const float4*)(cb + (size_t)w * DIM + lane * 4);
    float s = v.x * v.x + v.y * v.y + v.z * v.z + v.w * v.w;
    #pragma unroll
    for (int off = 32; off > 0; off >>= 1) s += __shfl_down(s, off);
    if (lane == 0) c2h[w] = 0.5f * s;
}

// ---------------- pack kernel: codebook -> pre-split, pre-swizzled image ----
// 512 chunk-blocks of 16 KB; chunk-block (kt*8+chunk) at h16 offset
// col*64 + p*8 holds: s = p ^ (col&7); s<4 -> f16-high of d [chunk*32+s*8..+7]
// of code kt*128+col; s>=4 -> f16-low residual. (Unchanged since R5.)
__global__ __launch_bounds__(256) void pack_kernel(const float* __restrict__ cb,
                                                   h16* __restrict__ Bp) {
    const int tid = blockIdx.x * 256 + threadIdx.x;
    const int code = tid >> 5;
    const int grp = tid & 31;
    float x[8];
    *(float4*)&x[0] = *(const float4*)(cb + (size_t)code * DIM + grp * 8);
    *(float4*)&x[4] = *(const float4*)(cb + (size_t)code * DIM + grp * 8 + 4);
    f16x8 hh, ll;
    split8(x, hh, ll);
    const int kt = code >> 7, col = code & 127;
    const int chunk = grp >> 2, s = grp & 3;
    const int ph = s ^ (col & 7), pl = (s + 4) ^ (col & 7);
    h16* base = Bp + ((size_t)(kt * 8 + chunk) * 8192) + col * 64;
    *(f16x8*)(base + ph * 8) = hh;
    *(f16x8*)(base + pl * 8) = ll;
}

// ---------------- main MFMA kernel ----------------
// R6 per-wave structure at 512 threads / BM=128: wave tile 32x64
// (2m x 4n of 16x16x32), A pre-split in regs, B streams via global_load_lds
// into ring-3 x 16 KB, counted vmcnt(2) keeps prefetch in flight across
// barriers. 3-pass split (hh + hl + lh; ll term ~1e-6 << top-2 gaps ~1e-2).
// NOTE launch_bounds 2nd arg: behaves as min BLOCKS/CU (R8 post-mortem):
// (512,2) -> 16 waves/CU -> 128-VGPR cap; body needs ~116.
__global__ __launch_bounds__(NTHREADS, 2) void vq_mfma_pk(
    const float* __restrict__ rep, const h16* __restrict__ Bp,
    const float* __restrict__ c2h, int* __restrict__ out) {

    __shared__ __align__(16) h16 ring[3][8192];   // 48 KB

    const int t = threadIdx.x;
    const int lane = t & 63;
    const int c15 = lane & 15;
    const int g = lane >> 4;              // k-group 0..3
    const int w = t >> 6;                 // wave 0..7
    const int wrow = (w >> 1) * 32;       // row group 0,32,64,96
    const int wcol = (w & 1) * 64;        // col half 0/64
    const int row0 = blockIdx.x * BM;

    // ---- A fragments: 2 row-subtiles x 8 chunks, load + split once ----
    f16x8 ah[2][8], al[2][8];
    #pragma unroll
    for (int m = 0; m < 2; ++m) {
        const float* ar = rep + (size_t)(row0 + wrow + m * 16 + c15) * DIM + g * 8;
        #pragma unroll
        for (int ch = 0; ch < 8; ++ch) {
            float x[8];
            *(float4*)&x[0] = *(const float4*)(ar + ch * 32);
            *(float4*)&x[4] = *(const float4*)(ar + ch * 32 + 4);
            split8(x, ah[m][ch], al[m][ch]);
        }
    }

    f32x4 acc[2][4];
    float best[2][4], cc[4];
    int bidx[2][4];
    #pragma unroll
    for (int m = 0; m < 2; ++m)
        #pragma unroll
        for (int n = 0; n < 4; ++n)
            #pragma unroll
            for (int r = 0; r < 4; ++r) acc[m][n][r] = 0.f;
    #pragma unroll
    for (int m = 0; m < 2; ++m)
        #pragma unroll
        for (int r = 0; r < 4; ++r) { best[m][r] = -3.4e38f; bidx[m][r] = 0; }

    // 512 threads cover a 16 KB chunk with 2 x 16B each
    auto issueB = [&](int q2, int slot) {
        const h16* src = Bp + (size_t)q2 * 8192 + t * 8;
        h16* dst = &ring[slot][t * 8];
        #pragma unroll
        for (int i = 0; i < 2; ++i)
            __builtin_amdgcn_global_load_lds(
                (const __attribute__((address_space(1))) uint32_t*)(src + i * 4096),
                (__attribute__((address_space(3))) uint32_t*)(dst + i * 4096),
                16, 0, 0);
    };

    // drain prologue A-loads so vmcnt counting below is exact
    asm volatile("s_waitcnt vmcnt(0)" ::: "memory");
    issueB(0, 0);
    issueB(1, 1);

    int bufq = 0;
    #pragma unroll 1
    for (int kt = 0; kt < NKT; ++kt) {
        const int ktbase = kt * BN;
        #pragma unroll
        for (int chunk = 0; chunk < 8; ++chunk) {
            const int q = kt * 8 + chunk;
            // q's 2 loads issued 2 steps ago; newest 2 outstanding are q+1's
            // prefetch -> vmcnt(2) proves q landed (older cc loads drain with
            // the same wait). lgkmcnt(0) drains my ds_reads before the
            // rendezvous (ring-slot overwrite hazard).
            if (q == NQ - 1) asm volatile("s_waitcnt vmcnt(0) lgkmcnt(0)" ::: "memory");
            else             asm volatile("s_waitcnt vmcnt(2) lgkmcnt(0)" ::: "memory");
            __builtin_amdgcn_s_barrier();
            __builtin_amdgcn_sched_barrier(0);   // rule 18: nothing crosses

            // cc BEFORE issueB so the newest 2 vmcnt entries stay the prefetch
            if (chunk == 0) {
                #pragma unroll
                for (int n = 0; n < 4; ++n) cc[n] = c2h[ktbase + wcol + n * 16 + c15];
            }
            if (q + 2 < NQ) {
                int slot = bufq + 2;
                if (slot >= 3) slot -= 3;
                issueB(q + 2, slot);
            }

            const h16* lb = &ring[bufq][0];
            #pragma unroll
            for (int n = 0; n < 4; ++n) {
                const int base = (wcol + n * 16 + c15) * 64;
                f16x8 bh = *(const f16x8*)&lb[base + ((g ^ (lane & 7)) << 3)];
                f16x8 bl = *(const f16x8*)&lb[base + (((4 + g) ^ (lane & 7)) << 3)];
                #pragma unroll
                for (int m = 0; m < 2; ++m) {
                    acc[m][n] = __builtin_amdgcn_mfma_f32_16x16x32_f16(ah[m][chunk], bh, acc[m][n], 0, 0, 0);
                    acc[m][n] = __builtin_amdgcn_mfma_f32_16x16x32_f16(ah[m][chunk], bl, acc[m][n], 0, 0, 0);
                    acc[m][n] = __builtin_amdgcn_mfma_f32_16x16x32_f16(al[m][chunk], bh, acc[m][n], 0, 0, 0);
                }
            }

            if (chunk == 7) {   // per-kt argmin epilogue (strict '>' = np tie rule)
                #pragma unroll
                for (int n = 0; n < 4; ++n) {
                    const int col = ktbase + wcol + n * 16 + c15;
                    #pragma unroll
                    for (int m = 0; m < 2; ++m)
                        #pragma unroll
                        for (int r = 0; r < 4; ++r) {
                            float s2 = acc[m][n][r] - cc[n];
                            if (s2 > best[m][r]) { best[m][r] = s2; bidx[m][r] = col; }
                            acc[m][n][r] = 0.f;
                        }
                }
            }
            bufq = (bufq + 1 == 3) ? 0 : bufq + 1;
        }
    }

    // ---- final reduce ----
    // Step 1: shfl across the 16 col-lanes (tie -> lower idx).
    // Step 2: two col-half waves cover each row -> combine via LDS scratch.
    // ring[0] is safe: after the q=511 barrier every wave reads ring[1] only.
    float* sv = (float*)&ring[0][0];      // [row 0..127][half 0..1] = 256 floats
    int* si = (int*)&ring[0][1024];       // byte 2048+ -> no overlap with sv
    #pragma unroll
    for (int m = 0; m < 2; ++m)
        #pragma unroll
        for (int r = 0; r < 4; ++r) {
            float bv = best[m][r];
            int bi = bidx[m][r];
            #pragma unroll
            for (int mask = 1; mask <= 8; mask <<= 1) {
                float ov = __shfl_xor(bv, mask);
                int oi = __shfl_xor(bi, mask);
                if (ov > bv || (ov == bv && oi < bi)) { bv = ov; bi = oi; }
            }
            if (c15 == 0) {
                const int rl = wrow + m * 16 + g * 4 + r;   // 0..127
                sv[rl * 2 + (w & 1)] = bv;
                si[rl * 2 + (w & 1)] = bi;
            }
        }
    __syncthreads();
    if (t < BM) {
        float va = sv[t * 2 + 0], vb = sv[t * 2 + 1];
        int ia = si[t * 2 + 0], ib = si[t * 2 + 1];
        bool pickb = (vb > va) || (vb == va && ib < ia);
        out[row0 + t] = pickb ? ib : ia;
    }
}

extern "C" void kernel_launch(void* const* d_in, const int* in_sizes, int n_in,
                              void* d_out, int out_size, void* d_ws, size_t ws_size,
                              hipStream_t stream) {
    const float* rep = (const float*)d_in[0];
    const float* cb = (const float*)d_in[1];
    const int N = in_sizes[0] / DIM;   // 65536
    const int K = in_sizes[1] / DIM;   // 8192
    float* c2h = (float*)d_ws;         // 32 KB
    h16* Bp = (h16*)((char*)d_ws + 32768);   // 8 MB (ws >= 8.4 MB, proven R5)
    int* out = (int*)d_out;

    c2_kernel<<<dim3((K * 64 + 255) / 256), dim3(256), 0, stream>>>(cb, c2h, K);
    pack_kernel<<<dim3(KCODES * 32 / 256), dim3(256), 0, stream>>>(cb, Bp);
    vq_mfma_pk<<<dim3(N / BM), dim3(NTHREADS), 0, stream>>>(rep, Bp, c2h, out);
}